// Round 1
// baseline (576.433 us; speedup 1.0000x reference)
//
#include <hip/hip_runtime.h>
#include <math.h>

#define BATCH 64
#define SLEN  480050          // 200 + 150*3199
#define TFR   3200            // frames
#define FLEN  200             // frame length
#define FSH   150             // shift
#define NBINS 128             // kept DFT bins
#define EPSF  1e-7f

// ws layout in floats
#define WS_PART 0             // 512 blocks * 2 = 1024
#define WS_MU   1024          // 64
#define WS_INV  1088          // 64
#define WS_COS  2048          // 200*128 = 25600
#define WS_SIN  27648         // 25600  (ends at 53248 floats = 208 KiB)

__global__ __launch_bounds__(256) void k_stats_partial(const float* __restrict__ x,
                                                       float* __restrict__ ws) {
    int blk = blockIdx.x;          // 0..511
    int b = blk >> 3, c = blk & 7;
    const float2* row = (const float2*)(x + (size_t)b * SLEN);
    const int n2 = SLEN / 2;       // 240025
    const int per = (n2 + 7) / 8;  // 30004
    int start = c * per;
    int end = start + per; if (end > n2) end = n2;
    float s = 0.f, q = 0.f;
    for (int i = start + threadIdx.x; i < end; i += 256) {
        float2 v = row[i];
        s += v.x + v.y;
        q += v.x * v.x + v.y * v.y;
    }
    #pragma unroll
    for (int off = 1; off < 64; off <<= 1) {
        s += __shfl_xor(s, off);
        q += __shfl_xor(q, off);
    }
    __shared__ float ls[4], lq[4];
    int wave = threadIdx.x >> 6, lane = threadIdx.x & 63;
    if (lane == 0) { ls[wave] = s; lq[wave] = q; }
    __syncthreads();
    if (threadIdx.x == 0) {
        float S2 = ls[0] + ls[1] + ls[2] + ls[3];
        float Q2 = lq[0] + lq[1] + lq[2] + lq[3];
        ws[WS_PART + blk * 2]     = S2;
        ws[WS_PART + blk * 2 + 1] = Q2;
    }
}

__global__ __launch_bounds__(64) void k_stats_final(float* __restrict__ ws) {
    int b = threadIdx.x;
    if (b < BATCH) {
        float s = 0.f, q = 0.f;
        #pragma unroll
        for (int c = 0; c < 8; ++c) {
            s += ws[WS_PART + (b * 8 + c) * 2];
            q += ws[WS_PART + (b * 8 + c) * 2 + 1];
        }
        float mean = s / (float)SLEN;
        float var  = q / (float)SLEN - mean * mean;
        float sd   = sqrtf(fmaxf(var, 0.f));
        ws[WS_MU  + b] = mean;
        ws[WS_INV + b] = 1.0f / (sd + EPSF);
    }
}

// transpose kernels [n][l] -> [l][n] for the 128 kept bins
__global__ __launch_bounds__(256) void k_transpose(const float* __restrict__ rk,
                                                   const float* __restrict__ ik,
                                                   float* __restrict__ ws) {
    int n = blockIdx.x;            // 0..127
    int l = threadIdx.x;           // 0..255
    if (l < FLEN) {
        ws[WS_COS + l * NBINS + n] = rk[n * FLEN + l];
        ws[WS_SIN + l * NBINS + n] = ik[n * FLEN + l];
    }
}

// main fused kernel: block = (32 frames) x (128 bins)
__global__ __launch_bounds__(256) void k_main(const float* __restrict__ x,
                                              const float* __restrict__ ws,
                                              float* __restrict__ out) {
    __shared__ float frame[32][204];   // pitch 204 floats = 816B (16B aligned rows)

    int b  = blockIdx.y;
    int t0 = blockIdx.x * 32;
    int tid = threadIdx.x;

    float mu  = ws[WS_MU  + b];
    float inv = ws[WS_INV + b];
    const float* xb = x + (size_t)b * SLEN;

    // stage 32 normalized frames into LDS
    for (int tt = 0; tt < 32; ++tt) {
        int base = (t0 + tt) * FSH;
        for (int l = tid; l < FLEN; l += 256)
            frame[tt][l] = (xb[base + l] - mu) * inv;
    }
    __syncthreads();

    int nq = tid & 31;         // 32 bin-groups of 4
    int tq = tid >> 5;         // 8 frame-groups of 4
    int n0 = nq * 4;
    int tl0 = tq * 4;

    const float4* cosT = (const float4*)(ws + WS_COS);
    const float4* sinT = (const float4*)(ws + WS_SIN);

    float ar[4][4], ai[4][4];
    #pragma unroll
    for (int tt = 0; tt < 4; ++tt)
        #pragma unroll
        for (int nn = 0; nn < 4; ++nn) { ar[tt][nn] = 0.f; ai[tt][nn] = 0.f; }

    for (int l = 0; l < FLEN; l += 4) {
        float4 c0 = cosT[(l + 0) * 32 + nq];
        float4 c1 = cosT[(l + 1) * 32 + nq];
        float4 c2 = cosT[(l + 2) * 32 + nq];
        float4 c3 = cosT[(l + 3) * 32 + nq];
        float4 s0 = sinT[(l + 0) * 32 + nq];
        float4 s1 = sinT[(l + 1) * 32 + nq];
        float4 s2 = sinT[(l + 2) * 32 + nq];
        float4 s3 = sinT[(l + 3) * 32 + nq];
        #pragma unroll
        for (int tt = 0; tt < 4; ++tt) {
            float4 f = *(const float4*)&frame[tl0 + tt][l];
            // j = 0
            ar[tt][0] = fmaf(f.x, c0.x, ar[tt][0]);
            ar[tt][1] = fmaf(f.x, c0.y, ar[tt][1]);
            ar[tt][2] = fmaf(f.x, c0.z, ar[tt][2]);
            ar[tt][3] = fmaf(f.x, c0.w, ar[tt][3]);
            ai[tt][0] = fmaf(f.x, s0.x, ai[tt][0]);
            ai[tt][1] = fmaf(f.x, s0.y, ai[tt][1]);
            ai[tt][2] = fmaf(f.x, s0.z, ai[tt][2]);
            ai[tt][3] = fmaf(f.x, s0.w, ai[tt][3]);
            // j = 1
            ar[tt][0] = fmaf(f.y, c1.x, ar[tt][0]);
            ar[tt][1] = fmaf(f.y, c1.y, ar[tt][1]);
            ar[tt][2] = fmaf(f.y, c1.z, ar[tt][2]);
            ar[tt][3] = fmaf(f.y, c1.w, ar[tt][3]);
            ai[tt][0] = fmaf(f.y, s1.x, ai[tt][0]);
            ai[tt][1] = fmaf(f.y, s1.y, ai[tt][1]);
            ai[tt][2] = fmaf(f.y, s1.z, ai[tt][2]);
            ai[tt][3] = fmaf(f.y, s1.w, ai[tt][3]);
            // j = 2
            ar[tt][0] = fmaf(f.z, c2.x, ar[tt][0]);
            ar[tt][1] = fmaf(f.z, c2.y, ar[tt][1]);
            ar[tt][2] = fmaf(f.z, c2.z, ar[tt][2]);
            ar[tt][3] = fmaf(f.z, c2.w, ar[tt][3]);
            ai[tt][0] = fmaf(f.z, s2.x, ai[tt][0]);
            ai[tt][1] = fmaf(f.z, s2.y, ai[tt][1]);
            ai[tt][2] = fmaf(f.z, s2.z, ai[tt][2]);
            ai[tt][3] = fmaf(f.z, s2.w, ai[tt][3]);
            // j = 3
            ar[tt][0] = fmaf(f.w, c3.x, ar[tt][0]);
            ar[tt][1] = fmaf(f.w, c3.y, ar[tt][1]);
            ar[tt][2] = fmaf(f.w, c3.z, ar[tt][2]);
            ar[tt][3] = fmaf(f.w, c3.w, ar[tt][3]);
            ai[tt][0] = fmaf(f.w, s3.x, ai[tt][0]);
            ai[tt][1] = fmaf(f.w, s3.y, ai[tt][1]);
            ai[tt][2] = fmaf(f.w, s3.z, ai[tt][2]);
            ai[tt][3] = fmaf(f.w, s3.w, ai[tt][3]);
        }
    }

    // magnitude -> log10
    float v[4][4];
    #pragma unroll
    for (int tt = 0; tt < 4; ++tt) {
        #pragma unroll
        for (int nn = 0; nn < 4; ++nn) {
            float m = sqrtf(ar[tt][nn] * ar[tt][nn] + ai[tt][nn] * ai[tt][nn]);
            m = fmaxf(m, EPSF);
            v[tt][nn] = __log2f(m) * 0.3010299956639812f;   // log10
        }
    }

    // per-(b,t) normalization over the 128 bins: lanes nq=0..31 x 4 regs
    #pragma unroll
    for (int tt = 0; tt < 4; ++tt) {
        float s = v[tt][0] + v[tt][1] + v[tt][2] + v[tt][3];
        float q = v[tt][0] * v[tt][0] + v[tt][1] * v[tt][1]
                + v[tt][2] * v[tt][2] + v[tt][3] * v[tt][3];
        #pragma unroll
        for (int off = 1; off < 32; off <<= 1) {
            s += __shfl_xor(s, off);
            q += __shfl_xor(q, off);
        }
        float mean = s * (1.0f / 128.0f);
        float var  = q * (1.0f / 128.0f) - mean * mean;
        float sd   = sqrtf(fmaxf(var, 0.f));
        float sc   = 1.0f / (sd + EPSF);
        #pragma unroll
        for (int nn = 0; nn < 4; ++nn)
            v[tt][nn] = (v[tt][nn] - mean) * sc;
    }

    // write: out[b][n][t], float4 over 4 consecutive t
    float* ob = out + (size_t)b * NBINS * TFR + t0 + tl0;
    #pragma unroll
    for (int nn = 0; nn < 4; ++nn) {
        float4 w = make_float4(v[0][nn], v[1][nn], v[2][nn], v[3][nn]);
        *(float4*)(ob + (size_t)(n0 + nn) * TFR) = w;
    }
}

extern "C" void kernel_launch(void* const* d_in, const int* in_sizes, int n_in,
                              void* d_out, int out_size, void* d_ws, size_t ws_size,
                              hipStream_t stream) {
    const float* x  = (const float*)d_in[0];
    const float* rk = (const float*)d_in[1];
    const float* ik = (const float*)d_in[2];
    float* out = (float*)d_out;
    float* ws  = (float*)d_ws;

    k_stats_partial<<<512, 256, 0, stream>>>(x, ws);
    k_stats_final<<<1, 64, 0, stream>>>(ws);
    k_transpose<<<NBINS, 256, 0, stream>>>(rk, ik, ws);
    k_main<<<dim3(TFR / 32, BATCH), 256, 0, stream>>>(x, ws, out);
}